// Round 5
// baseline (1301.623 us; speedup 1.0000x reference)
//
#include <hip/hip_runtime.h>
#include <math.h>

#define HWQ 625      // 25*25
#define NPOSQ 390625 // 625*625
#define NB 4
#define NCH 1024

typedef __attribute__((ext_vector_type(8))) short bf16x8;
typedef __attribute__((ext_vector_type(4))) float f32x4;

__device__ inline unsigned short f2bf(float x) {
    union { float f; unsigned int u; } c; c.f = x;
    unsigned int u = c.u;
    return (unsigned short)((u + 0x7fffu + ((u >> 16) & 1u)) >> 16); // RNE
}

// ---------------- pack: W1P [9e][9t][20co], bias dups ----------------
__global__ void pack_misc_kernel(const float* __restrict__ W1, const float* __restrict__ b1,
                                 const float* __restrict__ b2,
                                 float* __restrict__ W1P, float* __restrict__ bL1,
                                 float* __restrict__ bL2)
{
    int t = blockIdx.x * blockDim.x + threadIdx.x;
    if (t < 1620) {
        int co = t % 20; int r = t / 20; int e = r / 9, t34 = r % 9;
        W1P[t] = (co < 10) ? W1[co * 81 + e * 9 + t34] : W1[(co - 10) * 81 + t34 * 9 + e];
    }
    if (t < 20) { bL1[t] = b1[t % 10]; bL2[t] = b2[t % 10]; }
}

// ---------------- pack layer-2 weights into MFMA A-fragment order ----------------
__global__ void pack_mfma_w2_kernel(const float* __restrict__ W2,
                                    unsigned short* __restrict__ Ablob)
{
    int t = blockIdx.x * blockDim.x + threadIdx.x;
    if (t >= 54 * 64) return;
    int frag = t >> 6, lane = t & 63;
    int g = frag / 27; int r1 = frag % 27; int kstep = r1 / 9; int dd = r1 % 9;
    int d3 = dd / 3, d4 = dd % 3;
    int co = lane & 15;
    unsigned short v[8];
#pragma unroll
    for (int j = 0; j < 8; ++j) {
        int k = kstep * 32 + ((lane >> 4) << 3) + j;
        float w = 0.0f;
        if (co < 10 && k < 90) {
            int ci = k / 9, e = k % 9, d1 = e / 3, d2 = e % 3;
            int tap = (g == 0) ? (d1 * 27 + d2 * 9 + d3 * 3 + d4)
                               : (d3 * 27 + d4 * 9 + d1 * 3 + d2);
            w = W2[(co * 10 + ci) * 81 + tap];
        }
        v[j] = f2bf(w);
    }
    uint4 val;
    val.x = (unsigned)v[0] | ((unsigned)v[1] << 16);
    val.y = (unsigned)v[2] | ((unsigned)v[3] << 16);
    val.z = (unsigned)v[4] | ((unsigned)v[5] << 16);
    val.w = (unsigned)v[6] | ((unsigned)v[7] << 16);
    *(uint4*)(Ablob + (size_t)frag * 512 + lane * 8) = val;
}

// ---------------- pack layer-3 weights: K=180 (both groups), rows 0/1 ----------------
__global__ void pack_mfma_w3_kernel(const float* __restrict__ W3,
                                    unsigned short* __restrict__ Ablob3)
{
    int t = blockIdx.x * blockDim.x + threadIdx.x;
    if (t >= 54 * 64) return;
    int frag = t >> 6, lane = t & 63;
    int kstep = frag / 9, dd = frag % 9;
    int d3 = dd / 3, d4 = dd % 3;
    int row = lane & 15;
    unsigned short v[8];
#pragma unroll
    for (int j = 0; j < 8; ++j) {
        int k = kstep * 32 + ((lane >> 4) << 3) + j;
        float w = 0.0f;
        if (k < 180) {
            int g = k / 90, rem = k - g * 90;
            int ci = rem / 9, e = rem % 9;
            if (row == g) {
                int d1 = e / 3, d2 = e % 3;
                int tap = (g == 0) ? (d1 * 27 + d2 * 9 + d3 * 3 + d4)
                                   : (d3 * 27 + d4 * 9 + d1 * 3 + d2);
                w = W3[ci * 81 + tap];
            }
        }
        v[j] = f2bf(w);
    }
    uint4 val;
    val.x = (unsigned)v[0] | ((unsigned)v[1] << 16);
    val.y = (unsigned)v[2] | ((unsigned)v[3] << 16);
    val.z = (unsigned)v[4] | ((unsigned)v[5] << 16);
    val.w = (unsigned)v[6] | ((unsigned)v[7] << 16);
    *(uint4*)(Ablob3 + (size_t)frag * 512 + lane * 8) = val;
}

// ---------------- inverse L2 norms over channel dim ----------------
__global__ void invnorm_kernel(const float* __restrict__ fA, const float* __restrict__ fB,
                               float* __restrict__ invA, float* __restrict__ invB)
{
    int idx = blockIdx.x * blockDim.x + threadIdx.x;
    if (idx >= NB * HWQ) return;
    const float* f = blockIdx.y ? fB : fA;
    float* o = blockIdx.y ? invB : invA;
    int b = idx / HWQ, m = idx - b * HWQ;
    const float* p = f + (size_t)b * NCH * HWQ + m;
    float s = 0.f;
    for (int c = 0; c < NCH; c += 4) {
        float x0 = p[(c + 0) * HWQ], x1 = p[(c + 1) * HWQ];
        float x2 = p[(c + 2) * HWQ], x3 = p[(c + 3) * HWQ];
        s += x0 * x0 + x1 * x1 + x2 * x2 + x3 * x3;
    }
    o[idx] = 1.0f / sqrtf(s + 1e-6f);
}

// ---------------- correlation GEMM ----------------
__global__ __launch_bounds__(256) void corr_gemm_kernel(
    const float* __restrict__ fA, const float* __restrict__ fB,
    const float* __restrict__ invA, const float* __restrict__ invB,
    float* __restrict__ corr)
{
    __shared__ float As[16][64];
    __shared__ float Bs[16][64];
    const int b = blockIdx.z;
    const int m0 = blockIdx.y * 64, n0 = blockIdx.x * 64;
    const int tid = threadIdx.x;
    const int tx = tid & 15, ty = tid >> 4;
    float acc[4][4] = {};
    const float* Ab = fA + (size_t)b * NCH * HWQ;
    const float* Bb = fB + (size_t)b * NCH * HWQ;
    for (int k0 = 0; k0 < NCH; k0 += 16) {
        for (int i = tid; i < 1024; i += 256) {
            int k = i >> 6, mm = i & 63;
            int gm = m0 + mm, gn = n0 + mm;
            As[k][mm] = (gm < HWQ) ? Ab[(k0 + k) * HWQ + gm] : 0.0f;
            Bs[k][mm] = (gn < HWQ) ? Bb[(k0 + k) * HWQ + gn] : 0.0f;
        }
        __syncthreads();
#pragma unroll
        for (int k = 0; k < 16; ++k) {
            float4 a4 = *(const float4*)&As[k][ty * 4];
            float4 b4 = *(const float4*)&Bs[k][tx * 4];
            float av[4] = {a4.x, a4.y, a4.z, a4.w};
            float bv[4] = {b4.x, b4.y, b4.z, b4.w};
#pragma unroll
            for (int i = 0; i < 4; ++i)
#pragma unroll
                for (int j = 0; j < 4; ++j)
                    acc[i][j] = fmaf(av[i], bv[j], acc[i][j]);
        }
        __syncthreads();
    }
#pragma unroll
    for (int i = 0; i < 4; ++i) {
        int m = m0 + ty * 4 + i;
        if (m >= HWQ) continue;
        float ia = invA[b * HWQ + m];
#pragma unroll
        for (int j = 0; j < 4; ++j) {
            int n = n0 + tx * 4 + j;
            if (n >= HWQ) continue;
            float v = acc[i][j] * ia * invB[b * HWQ + n];
            v = fmaxf(v, 0.0f);
            v = v / sqrtf(v * v + 1e-6f);
            corr[((size_t)b * HWQ + m) * HWQ + n] = v;
        }
    }
}

// ---------------- mutual matching helpers ----------------
__global__ void rowmax_kernel(const float* __restrict__ s, float* __restrict__ rmax)
{
    int row = blockIdx.x * 4 + (threadIdx.x >> 6);
    int lane = threadIdx.x & 63;
    if (row >= NB * HWQ) return;
    const float* p = s + (size_t)row * HWQ;
    float v = -1e30f;
    for (int n = lane; n < HWQ; n += 64) v = fmaxf(v, p[n]);
    for (int off = 32; off; off >>= 1) v = fmaxf(v, __shfl_xor(v, off));
    if (lane == 0) rmax[row] = v;
}

__global__ void colmax_kernel(const float* __restrict__ s, float* __restrict__ cmax)
{
    int b = blockIdx.x;
    int col = blockIdx.y * 128 + threadIdx.x;
    if (col >= HWQ) return;
    const float* p = s + (size_t)b * NPOSQ + col;
    float v = -1e30f;
    for (int m = 0; m < HWQ; ++m) v = fmaxf(v, p[m * HWQ]);
    cmax[b * HWQ + col] = v;
}

__global__ void mm_apply_kernel(const float* __restrict__ s, const float* __restrict__ rmax,
                                const float* __restrict__ cmax, float* __restrict__ out)
{
    int idx = blockIdx.x * blockDim.x + threadIdx.x;
    if (idx >= NB * NPOSQ) return;
    int b = idx / NPOSQ, rem = idx - b * NPOSQ;
    int m = rem / HWQ, n = rem - m * HWQ;
    float v = s[idx];
    out[idx] = v * v * v / ((rmax[b * HWQ + m] + 1e-5f) * (cmax[b * HWQ + n] + 1e-5f));
}

// ---------------- layer 1: VALU conv, weights in LDS, bf16 out ----------------
__global__ __launch_bounds__(192) void conv4d_l1(
    const float* __restrict__ corr, const float* __restrict__ W1P,
    const float* __restrict__ bL1, unsigned short* __restrict__ x1)
{
    __shared__ float sp[9 * 784]; // 9 x 28 x 28
    __shared__ float wl[1620];
    const int f12 = blockIdx.x;
    const float* in = corr + (size_t)blockIdx.z * NPOSQ;
    unsigned short* out = x1 + (size_t)blockIdx.z * 20 * NPOSQ;
    const int f1 = f12 / 25, f2 = f12 - f1 * 25;
    const int tid = threadIdx.x;

    for (int i = tid; i < 9 * 784; i += 192) sp[i] = 0.0f;
    for (int i = tid; i < 1620; i += 192) wl[i] = W1P[i];

    const int tt = (tid < 169) ? tid : 0;
    const int ty = tt / 13, tx = tt - ty * 13;
    const int r0 = ty * 2, c0 = tx * 2;

    float acc[20][4];
#pragma unroll
    for (int co = 0; co < 20; ++co) {
        float bv = bL1[co];
        acc[co][0] = bv; acc[co][1] = bv; acc[co][2] = bv; acc[co][3] = bv;
    }

    __syncthreads();
    for (int i = tid; i < 5625; i += 192) {
        int e = i / 625, q = i - e * 625;
        int d1 = e / 3, d2 = e - d1 * 3;
        int f1n = f1 + d1 - 1, f2n = f2 + d2 - 1;
        float v = 0.0f;
        if (((unsigned)f1n < 25u) & ((unsigned)f2n < 25u))
            v = in[(f1n * 25 + f2n) * HWQ + q];
        int rr = q / 25, cc = q - rr * 25;
        sp[e * 784 + (rr + 1) * 28 + (cc + 1)] = v;
    }
    __syncthreads();

#pragma unroll 1
    for (int e = 0; e < 9; ++e) {
        float win[16];
        const int base = e * 784 + r0 * 28 + c0;
#pragma unroll
        for (int a = 0; a < 4; ++a)
#pragma unroll
            for (int bb = 0; bb < 4; ++bb)
                win[a * 4 + bb] = sp[base + a * 28 + bb];
#pragma unroll
        for (int t34 = 0; t34 < 9; ++t34) {
            int d3 = t34 / 3, d4 = t34 - d3 * 3;
            float x0 = win[d3 * 4 + d4], x1v = win[d3 * 4 + d4 + 1];
            float x2v = win[(d3 + 1) * 4 + d4], x3v = win[(d3 + 1) * 4 + d4 + 1];
            const float* wp = wl + (e * 9 + t34) * 20;
#pragma unroll
            for (int c4 = 0; c4 < 5; ++c4) {
                float4 w4 = *(const float4*)(wp + c4 * 4);
                float wv[4] = {w4.x, w4.y, w4.z, w4.w};
#pragma unroll
                for (int q4 = 0; q4 < 4; ++q4) {
                    int co = c4 * 4 + q4;
                    acc[co][0] = fmaf(x0, wv[q4], acc[co][0]);
                    acc[co][1] = fmaf(x1v, wv[q4], acc[co][1]);
                    acc[co][2] = fmaf(x2v, wv[q4], acc[co][2]);
                    acc[co][3] = fmaf(x3v, wv[q4], acc[co][3]);
                }
            }
        }
    }

    if (tid < 169) {
#pragma unroll
        for (int co = 0; co < 20; ++co) {
            unsigned short* op = out + (size_t)co * NPOSQ + f12 * 625;
#pragma unroll
            for (int i = 0; i < 2; ++i)
#pragma unroll
                for (int j = 0; j < 2; ++j) {
                    int f3 = r0 + i, f4 = c0 + j;
                    if (f3 < 25 && f4 < 25)
                        op[f3 * 25 + f4] = f2bf(fmaxf(acc[co][i * 2 + j], 0.0f));
                }
        }
    }
}

// ---------------- MFMA conv core (layers 2 & 3) ----------------
// LDS: halo grid rows = u*27+v (u,v in 0..26 <-> f3,f4 in -1..25), 736 rows x 36 k-slots bf16.
// Inner loop: j outer, dd fully unrolled -> ds_read_b64 with compile-time immediate
// offsets ((d3*27+d4)*72). A-frags register-hoisted per kstep.
#define L2S 36
#define L2ROWS 736

// staging descriptor precompute shared by L2/L3
#define STAGE_PRE()                                                         \
    int qoff_[6]; unsigned dsto_[6]; unsigned inqm = 0;                     \
    _Pragma("unroll")                                                       \
    for (int it = 0; it < 6; ++it) {                                        \
        int task = tid + it * 512;                                          \
        int qp = task >> 2;                                                 \
        int u = qp / 27, v = qp - u * 27;                                   \
        int f3i = u - 1, f4i = v - 1;                                       \
        bool inq = (task < 2916) & ((unsigned)f3i < 25u) & ((unsigned)f4i < 25u); \
        if (inq) inqm |= (1u << it);                                        \
        qoff_[it] = f3i * 25 + f4i;                                         \
        dsto_[it] = (task < 2916) ? (unsigned)(qp * L2S + kg * 8) : 0u;     \
    }

#define STAGE_KSTEP(INPTR)                                                  \
    _Pragma("unroll")                                                       \
    for (int it = 0; it < 6; ++it) {                                        \
        if (tid + it * 512 < 2916) {                                        \
            bool inq = (inqm >> it) & 1;                                    \
            int qoff = qoff_[it];                                           \
            unsigned short vals[8];                                         \
            _Pragma("unroll")                                               \
            for (int j = 0; j < 8; ++j)                                     \
                vals[j] = (inq && ((vmask >> j) & 1)) ? (INPTR)[poff[j] + qoff] \
                                                      : (unsigned short)0;  \
            unsigned short* dst = sp + dsto_[it];                           \
            uint2 w0, w1;                                                   \
            w0.x = (unsigned)vals[0] | ((unsigned)vals[1] << 16);           \
            w0.y = (unsigned)vals[2] | ((unsigned)vals[3] << 16);           \
            w1.x = (unsigned)vals[4] | ((unsigned)vals[5] << 16);           \
            w1.y = (unsigned)vals[6] | ((unsigned)vals[7] << 16);           \
            *(uint2*)dst = w0;                                              \
            *(uint2*)(dst + 4) = w1;                                        \
        }                                                                   \
    }

#define MFMA_JDD(AF)                                                        \
    _Pragma("unroll")                                                       \
    for (int j = 0; j < 7; ++j) {                                           \
        if (j < 6 || wave < 2) {                                            \
            const int t = wave + j * 8;                                     \
            const int f3 = t >> 1, h = t & 1;                               \
            const unsigned short* bp = sp + (f3 * 27 + h * 16 + lo16) * L2S + kqg; \
            _Pragma("unroll")                                               \
            for (int dd = 0; dd < 9; ++dd) {                                \
                const int d3 = dd / 3, d4 = dd - d3 * 3;                    \
                const unsigned short* rp = bp + (d3 * 27 + d4) * L2S;       \
                uint2 p0 = *(const uint2*)rp;                               \
                uint2 p1 = *(const uint2*)(rp + 4);                         \
                union { unsigned u[4]; bf16x8 v; } cv;                      \
                cv.u[0] = p0.x; cv.u[1] = p0.y; cv.u[2] = p1.x; cv.u[3] = p1.y; \
                acc[j] = __builtin_amdgcn_mfma_f32_16x16x32_bf16(AF[dd], cv.v, acc[j], 0, 0, 0); \
            }                                                               \
        }                                                                   \
    }

__global__ __launch_bounds__(512, 6) void conv4d_mfma_l2(
    const unsigned short* __restrict__ x1, const unsigned short* __restrict__ Ablob,
    const float* __restrict__ bL2, unsigned short* __restrict__ x2)
{
    __shared__ alignas(16) unsigned short sp[L2ROWS * L2S]; // 52992 B
    const int f12 = blockIdx.x, g = blockIdx.y;
    const unsigned short* in = x1 + (size_t)blockIdx.z * 20 * NPOSQ;
    unsigned short* out = x2 + (size_t)blockIdx.z * 20 * NPOSQ;
    const int f1 = f12 / 25, f2 = f12 - f1 * 25;
    const int tid = threadIdx.x, wave = tid >> 6, lane = tid & 63;
    const int lo16 = lane & 15, kqg = (lane >> 4) << 3;
    const int kg = tid & 3;

    f32x4 acc[7];
#pragma unroll
    for (int j = 0; j < 7; ++j) acc[j] = (f32x4){0.f, 0.f, 0.f, 0.f};
    const unsigned short* Ag = Ablob + (size_t)g * 27 * 512;

    STAGE_PRE();

#pragma unroll 1
    for (int kstep = 0; kstep < 3; ++kstep) {
        unsigned poff[8];
        unsigned vmask = 0;
        const int kbase = kstep * 32 + kg * 8;
#pragma unroll
        for (int j = 0; j < 8; ++j) {
            int cie = kbase + j;
            int ci = cie / 9, e = cie - ci * 9;
            int f1n = f1 + e / 3 - 1, f2n = f2 + e % 3 - 1;
            if ((cie < 90) & ((unsigned)f1n < 25u) & ((unsigned)f2n < 25u)) vmask |= (1u << j);
            poff[j] = (unsigned)((g * 10 + ci) * NPOSQ + (f1n * 25 + f2n) * 625);
        }
        __syncthreads();
        STAGE_KSTEP(in);
        __syncthreads();
        bf16x8 af[9];
#pragma unroll
        for (int dd = 0; dd < 9; ++dd)
            af[dd] = *(const bf16x8*)(Ag + (size_t)(kstep * 9 + dd) * 512 + lane * 8);
        MFMA_JDD(af);
    }

    int t = wave;
    for (int j = 0; j < 7; ++j, t += 8) {
        if (t < 50) {
            int f3 = t >> 1, h = t & 1;
            int f4 = h * 16 + lo16;
            if (f4 < 25) {
#pragma unroll
                for (int r = 0; r < 4; ++r) {
                    int co = (lane >> 4) * 4 + r;
                    if (co < 10) {
                        float v = acc[j][r] + bL2[g * 10 + co];
                        out[(size_t)(g * 10 + co) * NPOSQ + f12 * 625 + f3 * 25 + f4] =
                            f2bf(fmaxf(v, 0.0f));
                    }
                }
            }
        }
    }
}

// Layer 3: K=180 (both groups), fused relu-sum, fp32 out to sbuf.
__global__ __launch_bounds__(512, 6) void conv4d_mfma_l3(
    const unsigned short* __restrict__ x2, const unsigned short* __restrict__ Ablob3,
    const float* __restrict__ b3p, float* __restrict__ sbuf)
{
    __shared__ alignas(16) unsigned short sp[L2ROWS * L2S];
    const int f12 = blockIdx.x;
    const unsigned short* in = x2 + (size_t)blockIdx.z * 20 * NPOSQ;
    float* out = sbuf + (size_t)blockIdx.z * NPOSQ;
    const int f1 = f12 / 25, f2 = f12 - f1 * 25;
    const int tid = threadIdx.x, wave = tid >> 6, lane = tid & 63;
    const int lo16 = lane & 15, kqg = (lane >> 4) << 3;
    const int kg = tid & 3;

    f32x4 acc[7];
#pragma unroll
    for (int j = 0; j < 7; ++j) acc[j] = (f32x4){0.f, 0.f, 0.f, 0.f};

    STAGE_PRE();

#pragma unroll 1
    for (int kstep = 0; kstep < 6; ++kstep) {
        unsigned poff[8];
        unsigned vmask = 0;
        const int kbase = kstep * 32 + kg * 8;
#pragma unroll
        for (int j = 0; j < 8; ++j) {
            int cie = kbase + j;
            int plane = cie / 9, e = cie - plane * 9;
            int f1n = f1 + e / 3 - 1, f2n = f2 + e % 3 - 1;
            if ((cie < 180) & ((unsigned)f1n < 25u) & ((unsigned)f2n < 25u)) vmask |= (1u << j);
            poff[j] = (unsigned)(plane * NPOSQ + (f1n * 25 + f2n) * 625);
        }
        __syncthreads();
        STAGE_KSTEP(in);
        __syncthreads();
        bf16x8 af[9];
#pragma unroll
        for (int dd = 0; dd < 9; ++dd)
            af[dd] = *(const bf16x8*)(Ablob3 + (size_t)(kstep * 9 + dd) * 512 + lane * 8);
        MFMA_JDD(af);
    }

    const float b3v = b3p[0];
    if ((lane >> 4) == 0) {
        int t = wave;
        for (int j = 0; j < 7; ++j, t += 8) {
            if (t < 50) {
                int f3 = t >> 1, h = t & 1;
                int f4 = h * 16 + lo16;
                if (f4 < 25) {
                    float s0 = fmaxf(acc[j][0] + b3v, 0.0f);
                    float s1 = fmaxf(acc[j][1] + b3v, 0.0f);
                    out[f12 * 625 + f3 * 25 + f4] = s0 + s1;
                }
            }
        }
    }
}

// ---------------- launch ----------------
extern "C" void kernel_launch(void* const* d_in, const int* in_sizes, int n_in,
                              void* d_out, int out_size, void* d_ws, size_t ws_size,
                              hipStream_t stream)
{
    const float* fA = (const float*)d_in[0];
    const float* fB = (const float*)d_in[1];
    const float* W1 = (const float*)d_in[2];
    const float* b1 = (const float*)d_in[3];
    const float* W2 = (const float*)d_in[4];
    const float* b2 = (const float*)d_in[5];
    const float* W3 = (const float*)d_in[6];
    const float* b3 = (const float*)d_in[7];
    float* out = (float*)d_out;
    float* ws = (float*)d_ws;

    float* invA = ws + 0;        // 2500
    float* invB = ws + 2500;     // 2500
    float* rmax = ws + 5000;     // 2500
    float* cmax = ws + 7500;     // 2500
    float* W1P  = ws + 10000;    // 1620
    float* bL1  = ws + 11620;    // 20
    float* bL2  = ws + 11640;    // 20
    unsigned short* Ablob2 = (unsigned short*)(ws + 12000); // 27648 us
    unsigned short* Ablob3 = (unsigned short*)(ws + 25824); // 27648 us
    float* corr = ws + 40000;    // 1562500
    float* sbuf = ws + 1602500;  // 1562500
    unsigned short* x1b = (unsigned short*)(ws + 3165000);

    const size_t REQ = (size_t)34415000 * 4;
    const bool fused = ws_size >= REQ;
    unsigned short* x2b = fused ? (unsigned short*)(ws + 18790000)
                                : (unsigned short*)(ws + 7080000);

    hipLaunchKernelGGL(pack_misc_kernel, dim3(7), dim3(256), 0, stream, W1, b1, b2, W1P, bL1, bL2);
    hipLaunchKernelGGL(pack_mfma_w2_kernel, dim3(14), dim3(256), 0, stream, W2, Ablob2);
    hipLaunchKernelGGL(pack_mfma_w3_kernel, dim3(14), dim3(256), 0, stream, W3, Ablob3);
    hipLaunchKernelGGL(invnorm_kernel, dim3(10, 2), dim3(256), 0, stream, fA, fB, invA, invB);
    hipLaunchKernelGGL(corr_gemm_kernel, dim3(10, 10, 4), dim3(256), 0, stream,
                       fA, fB, invA, invB, corr);
    hipLaunchKernelGGL(rowmax_kernel, dim3(625), dim3(256), 0, stream, corr, rmax);
    hipLaunchKernelGGL(colmax_kernel, dim3(4, 5), dim3(128), 0, stream, corr, cmax);
    hipLaunchKernelGGL(mm_apply_kernel, dim3(6104), dim3(256), 0, stream, corr, rmax, cmax, corr);

    if (fused) {
        hipLaunchKernelGGL(conv4d_l1, dim3(625, 1, NB), dim3(192), 0, stream, corr, W1P, bL1, x1b);
        hipLaunchKernelGGL(conv4d_mfma_l2, dim3(625, 2, NB), dim3(512), 0, stream,
                           x1b, Ablob2, bL2, x2b);
        hipLaunchKernelGGL(conv4d_mfma_l3, dim3(625, 1, NB), dim3(512), 0, stream,
                           x2b, Ablob3, b3, sbuf);
    } else {
        for (int b = 0; b < NB; ++b) {
            hipLaunchKernelGGL(conv4d_l1, dim3(625, 1, 1), dim3(192), 0, stream,
                               corr + (size_t)b * NPOSQ, W1P, bL1, x1b);
            hipLaunchKernelGGL(conv4d_mfma_l2, dim3(625, 2, 1), dim3(512), 0, stream,
                               x1b, Ablob2, bL2, x2b);
            hipLaunchKernelGGL(conv4d_mfma_l3, dim3(625, 1, 1), dim3(512), 0, stream,
                               x2b, Ablob3, b3, sbuf + (size_t)b * NPOSQ);
        }
    }

    hipLaunchKernelGGL(rowmax_kernel, dim3(625), dim3(256), 0, stream, sbuf, rmax);
    hipLaunchKernelGGL(colmax_kernel, dim3(4, 5), dim3(128), 0, stream, sbuf, cmax);
    hipLaunchKernelGGL(mm_apply_kernel, dim3(6104), dim3(256), 0, stream, sbuf, rmax, cmax, out);
}

// Round 6
// 1075.285 us; speedup vs baseline: 1.2105x; 1.2105x over previous
//
#include <hip/hip_runtime.h>
#include <math.h>

#define HWQ 625      // 25*25
#define NPOSQ 390625 // 625*625
#define NB 4
#define NCH 1024

typedef __attribute__((ext_vector_type(8))) short bf16x8;
typedef __attribute__((ext_vector_type(4))) float f32x4;

__device__ inline unsigned short f2bf(float x) {
    union { float f; unsigned int u; } c; c.f = x;
    unsigned int u = c.u;
    return (unsigned short)((u + 0x7fffu + ((u >> 16) & 1u)) >> 16); // RNE
}

// ---------------- pack: W1P [9e][9t][20co], bias dups ----------------
__global__ void pack_misc_kernel(const float* __restrict__ W1, const float* __restrict__ b1,
                                 const float* __restrict__ b2,
                                 float* __restrict__ W1P, float* __restrict__ bL1,
                                 float* __restrict__ bL2)
{
    int t = blockIdx.x * blockDim.x + threadIdx.x;
    if (t < 1620) {
        int co = t % 20; int r = t / 20; int e = r / 9, t34 = r % 9;
        W1P[t] = (co < 10) ? W1[co * 81 + e * 9 + t34] : W1[(co - 10) * 81 + t34 * 9 + e];
    }
    if (t < 20) { bL1[t] = b1[t % 10]; bL2[t] = b2[t % 10]; }
}

// ---------------- pack layer-2 weights into MFMA A-fragment order ----------------
__global__ void pack_mfma_w2_kernel(const float* __restrict__ W2,
                                    unsigned short* __restrict__ Ablob)
{
    int t = blockIdx.x * blockDim.x + threadIdx.x;
    if (t >= 54 * 64) return;
    int frag = t >> 6, lane = t & 63;
    int g = frag / 27; int r1 = frag % 27; int kstep = r1 / 9; int dd = r1 % 9;
    int d3 = dd / 3, d4 = dd % 3;
    int co = lane & 15;
    unsigned short v[8];
#pragma unroll
    for (int j = 0; j < 8; ++j) {
        int k = kstep * 32 + ((lane >> 4) << 3) + j;
        float w = 0.0f;
        if (co < 10 && k < 90) {
            int ci = k / 9, e = k % 9, d1 = e / 3, d2 = e % 3;
            int tap = (g == 0) ? (d1 * 27 + d2 * 9 + d3 * 3 + d4)
                               : (d3 * 27 + d4 * 9 + d1 * 3 + d2);
            w = W2[(co * 10 + ci) * 81 + tap];
        }
        v[j] = f2bf(w);
    }
    uint4 val;
    val.x = (unsigned)v[0] | ((unsigned)v[1] << 16);
    val.y = (unsigned)v[2] | ((unsigned)v[3] << 16);
    val.z = (unsigned)v[4] | ((unsigned)v[5] << 16);
    val.w = (unsigned)v[6] | ((unsigned)v[7] << 16);
    *(uint4*)(Ablob + (size_t)frag * 512 + lane * 8) = val;
}

// ---------------- pack layer-3 weights: K=180 (both groups), rows 0/1 ----------------
__global__ void pack_mfma_w3_kernel(const float* __restrict__ W3,
                                    unsigned short* __restrict__ Ablob3)
{
    int t = blockIdx.x * blockDim.x + threadIdx.x;
    if (t >= 54 * 64) return;
    int frag = t >> 6, lane = t & 63;
    int kstep = frag / 9, dd = frag % 9;
    int d3 = dd / 3, d4 = dd % 3;
    int row = lane & 15;
    unsigned short v[8];
#pragma unroll
    for (int j = 0; j < 8; ++j) {
        int k = kstep * 32 + ((lane >> 4) << 3) + j;
        float w = 0.0f;
        if (k < 180) {
            int g = k / 90, rem = k - g * 90;
            int ci = rem / 9, e = rem % 9;
            if (row == g) {
                int d1 = e / 3, d2 = e % 3;
                int tap = (g == 0) ? (d1 * 27 + d2 * 9 + d3 * 3 + d4)
                                   : (d3 * 27 + d4 * 9 + d1 * 3 + d2);
                w = W3[ci * 81 + tap];
            }
        }
        v[j] = f2bf(w);
    }
    uint4 val;
    val.x = (unsigned)v[0] | ((unsigned)v[1] << 16);
    val.y = (unsigned)v[2] | ((unsigned)v[3] << 16);
    val.z = (unsigned)v[4] | ((unsigned)v[5] << 16);
    val.w = (unsigned)v[6] | ((unsigned)v[7] << 16);
    *(uint4*)(Ablob3 + (size_t)frag * 512 + lane * 8) = val;
}

// ---------------- inverse L2 norms over channel dim ----------------
__global__ void invnorm_kernel(const float* __restrict__ fA, const float* __restrict__ fB,
                               float* __restrict__ invA, float* __restrict__ invB)
{
    int idx = blockIdx.x * blockDim.x + threadIdx.x;
    if (idx >= NB * HWQ) return;
    const float* f = blockIdx.y ? fB : fA;
    float* o = blockIdx.y ? invB : invA;
    int b = idx / HWQ, m = idx - b * HWQ;
    const float* p = f + (size_t)b * NCH * HWQ + m;
    float s = 0.f;
    for (int c = 0; c < NCH; c += 4) {
        float x0 = p[(c + 0) * HWQ], x1 = p[(c + 1) * HWQ];
        float x2 = p[(c + 2) * HWQ], x3 = p[(c + 3) * HWQ];
        s += x0 * x0 + x1 * x1 + x2 * x2 + x3 * x3;
    }
    o[idx] = 1.0f / sqrtf(s + 1e-6f);
}

// ---------------- correlation GEMM ----------------
__global__ __launch_bounds__(256) void corr_gemm_kernel(
    const float* __restrict__ fA, const float* __restrict__ fB,
    const float* __restrict__ invA, const float* __restrict__ invB,
    float* __restrict__ corr)
{
    __shared__ float As[16][64];
    __shared__ float Bs[16][64];
    const int b = blockIdx.z;
    const int m0 = blockIdx.y * 64, n0 = blockIdx.x * 64;
    const int tid = threadIdx.x;
    const int tx = tid & 15, ty = tid >> 4;
    float acc[4][4] = {};
    const float* Ab = fA + (size_t)b * NCH * HWQ;
    const float* Bb = fB + (size_t)b * NCH * HWQ;
    for (int k0 = 0; k0 < NCH; k0 += 16) {
        for (int i = tid; i < 1024; i += 256) {
            int k = i >> 6, mm = i & 63;
            int gm = m0 + mm, gn = n0 + mm;
            As[k][mm] = (gm < HWQ) ? Ab[(k0 + k) * HWQ + gm] : 0.0f;
            Bs[k][mm] = (gn < HWQ) ? Bb[(k0 + k) * HWQ + gn] : 0.0f;
        }
        __syncthreads();
#pragma unroll
        for (int k = 0; k < 16; ++k) {
            float4 a4 = *(const float4*)&As[k][ty * 4];
            float4 b4 = *(const float4*)&Bs[k][tx * 4];
            float av[4] = {a4.x, a4.y, a4.z, a4.w};
            float bv[4] = {b4.x, b4.y, b4.z, b4.w};
#pragma unroll
            for (int i = 0; i < 4; ++i)
#pragma unroll
                for (int j = 0; j < 4; ++j)
                    acc[i][j] = fmaf(av[i], bv[j], acc[i][j]);
        }
        __syncthreads();
    }
#pragma unroll
    for (int i = 0; i < 4; ++i) {
        int m = m0 + ty * 4 + i;
        if (m >= HWQ) continue;
        float ia = invA[b * HWQ + m];
#pragma unroll
        for (int j = 0; j < 4; ++j) {
            int n = n0 + tx * 4 + j;
            if (n >= HWQ) continue;
            float v = acc[i][j] * ia * invB[b * HWQ + n];
            v = fmaxf(v, 0.0f);
            v = v / sqrtf(v * v + 1e-6f);
            corr[((size_t)b * HWQ + m) * HWQ + n] = v;
        }
    }
}

// ---------------- mutual matching helpers ----------------
__global__ void rowmax_kernel(const float* __restrict__ s, float* __restrict__ rmax)
{
    int row = blockIdx.x * 4 + (threadIdx.x >> 6);
    int lane = threadIdx.x & 63;
    if (row >= NB * HWQ) return;
    const float* p = s + (size_t)row * HWQ;
    float v = -1e30f;
    for (int n = lane; n < HWQ; n += 64) v = fmaxf(v, p[n]);
    for (int off = 32; off; off >>= 1) v = fmaxf(v, __shfl_xor(v, off));
    if (lane == 0) rmax[row] = v;
}

__global__ void colmax_kernel(const float* __restrict__ s, float* __restrict__ cmax)
{
    int b = blockIdx.x;
    int col = blockIdx.y * 128 + threadIdx.x;
    if (col >= HWQ) return;
    const float* p = s + (size_t)b * NPOSQ + col;
    float v = -1e30f;
    for (int m = 0; m < HWQ; ++m) v = fmaxf(v, p[m * HWQ]);
    cmax[b * HWQ + col] = v;
}

__global__ void mm_apply_kernel(const float* __restrict__ s, const float* __restrict__ rmax,
                                const float* __restrict__ cmax, float* __restrict__ out)
{
    int idx = blockIdx.x * blockDim.x + threadIdx.x;
    if (idx >= NB * NPOSQ) return;
    int b = idx / NPOSQ, rem = idx - b * NPOSQ;
    int m = rem / HWQ, n = rem - m * HWQ;
    float v = s[idx];
    out[idx] = v * v * v / ((rmax[b * HWQ + m] + 1e-5f) * (cmax[b * HWQ + n] + 1e-5f));
}

// ---------------- layer 1: VALU conv, weights in LDS, bf16 out ----------------
__global__ __launch_bounds__(192) void conv4d_l1(
    const float* __restrict__ corr, const float* __restrict__ W1P,
    const float* __restrict__ bL1, unsigned short* __restrict__ x1)
{
    __shared__ float sp[9 * 784]; // 9 x 28 x 28
    __shared__ float wl[1620];
    const int f12 = blockIdx.x;
    const float* in = corr + (size_t)blockIdx.z * NPOSQ;
    unsigned short* out = x1 + (size_t)blockIdx.z * 20 * NPOSQ;
    const int f1 = f12 / 25, f2 = f12 - f1 * 25;
    const int tid = threadIdx.x;

    for (int i = tid; i < 9 * 784; i += 192) sp[i] = 0.0f;
    for (int i = tid; i < 1620; i += 192) wl[i] = W1P[i];

    const int tt = (tid < 169) ? tid : 0;
    const int ty = tt / 13, tx = tt - ty * 13;
    const int r0 = ty * 2, c0 = tx * 2;

    float acc[20][4];
#pragma unroll
    for (int co = 0; co < 20; ++co) {
        float bv = bL1[co];
        acc[co][0] = bv; acc[co][1] = bv; acc[co][2] = bv; acc[co][3] = bv;
    }

    __syncthreads();
    for (int i = tid; i < 5625; i += 192) {
        int e = i / 625, q = i - e * 625;
        int d1 = e / 3, d2 = e - d1 * 3;
        int f1n = f1 + d1 - 1, f2n = f2 + d2 - 1;
        float v = 0.0f;
        if (((unsigned)f1n < 25u) & ((unsigned)f2n < 25u))
            v = in[(f1n * 25 + f2n) * HWQ + q];
        int rr = q / 25, cc = q - rr * 25;
        sp[e * 784 + (rr + 1) * 28 + (cc + 1)] = v;
    }
    __syncthreads();

#pragma unroll 1
    for (int e = 0; e < 9; ++e) {
        float win[16];
        const int base = e * 784 + r0 * 28 + c0;
#pragma unroll
        for (int a = 0; a < 4; ++a)
#pragma unroll
            for (int bb = 0; bb < 4; ++bb)
                win[a * 4 + bb] = sp[base + a * 28 + bb];
#pragma unroll
        for (int t34 = 0; t34 < 9; ++t34) {
            int d3 = t34 / 3, d4 = t34 - d3 * 3;
            float x0 = win[d3 * 4 + d4], x1v = win[d3 * 4 + d4 + 1];
            float x2v = win[(d3 + 1) * 4 + d4], x3v = win[(d3 + 1) * 4 + d4 + 1];
            const float* wp = wl + (e * 9 + t34) * 20;
#pragma unroll
            for (int c4 = 0; c4 < 5; ++c4) {
                float4 w4 = *(const float4*)(wp + c4 * 4);
                float wv[4] = {w4.x, w4.y, w4.z, w4.w};
#pragma unroll
                for (int q4 = 0; q4 < 4; ++q4) {
                    int co = c4 * 4 + q4;
                    acc[co][0] = fmaf(x0, wv[q4], acc[co][0]);
                    acc[co][1] = fmaf(x1v, wv[q4], acc[co][1]);
                    acc[co][2] = fmaf(x2v, wv[q4], acc[co][2]);
                    acc[co][3] = fmaf(x3v, wv[q4], acc[co][3]);
                }
            }
        }
    }

    if (tid < 169) {
#pragma unroll
        for (int co = 0; co < 20; ++co) {
            unsigned short* op = out + (size_t)co * NPOSQ + f12 * 625;
#pragma unroll
            for (int i = 0; i < 2; ++i)
#pragma unroll
                for (int j = 0; j < 2; ++j) {
                    int f3 = r0 + i, f4 = c0 + j;
                    if (f3 < 25 && f4 < 25)
                        op[f3 * 25 + f4] = f2bf(fmaxf(acc[co][i * 2 + j], 0.0f));
                }
        }
    }
}

// ---------------- MFMA conv core (layers 2 & 3) ----------------
// LDS: halo grid rows = u*27+v (u,v in 0..26 <-> f3,f4 in -1..25), 736 rows x 36 k-slots bf16.
// dd outer (A-frag double-buffered, 2 live), j inner with hoisted base addrs bpo[7];
// the dd displacement (d3*27+d4)*72B is a compile-time DS offset immediate.
#define L2S 36
#define L2ROWS 736

#define STAGE_PRE()                                                         \
    int qoff_[6]; unsigned dsto_[6]; unsigned inqm = 0;                     \
    _Pragma("unroll")                                                       \
    for (int it = 0; it < 6; ++it) {                                        \
        int task = tid + it * 512;                                          \
        int qp = task >> 2;                                                 \
        int u = qp / 27, v = qp - u * 27;                                   \
        int f3i = u - 1, f4i = v - 1;                                       \
        bool inq = (task < 2916) & ((unsigned)f3i < 25u) & ((unsigned)f4i < 25u); \
        if (inq) inqm |= (1u << it);                                        \
        qoff_[it] = f3i * 25 + f4i;                                         \
        dsto_[it] = (task < 2916) ? (unsigned)(qp * L2S + kg * 8) : 0u;     \
    }                                                                       \
    unsigned bpo_[7];                                                       \
    _Pragma("unroll")                                                       \
    for (int j = 0; j < 7; ++j) {                                           \
        int t = wave + j * 8;                                               \
        int f3 = t >> 1, h = t & 1;                                         \
        bpo_[j] = (unsigned)(((f3 * 27 + h * 16 + lo16) * L2S + kqg) * 2);  \
    }

#define STAGE_KSTEP(INPTR)                                                  \
    _Pragma("unroll")                                                       \
    for (int it = 0; it < 6; ++it) {                                        \
        if (tid + it * 512 < 2916) {                                        \
            bool inq = (inqm >> it) & 1;                                    \
            int qoff = qoff_[it];                                           \
            unsigned short vals[8];                                         \
            _Pragma("unroll")                                               \
            for (int j = 0; j < 8; ++j)                                     \
                vals[j] = (inq && ((vmask >> j) & 1)) ? (INPTR)[poff[j] + qoff] \
                                                      : (unsigned short)0;  \
            unsigned short* dst = sp + dsto_[it];                           \
            uint2 w0, w1;                                                   \
            w0.x = (unsigned)vals[0] | ((unsigned)vals[1] << 16);           \
            w0.y = (unsigned)vals[2] | ((unsigned)vals[3] << 16);           \
            w1.x = (unsigned)vals[4] | ((unsigned)vals[5] << 16);           \
            w1.y = (unsigned)vals[6] | ((unsigned)vals[7] << 16);           \
            *(uint2*)dst = w0;                                              \
            *(uint2*)(dst + 4) = w1;                                        \
        }                                                                   \
    }

#define MFMA_KSTEP(ABASE)                                                   \
    {                                                                       \
        bf16x8 afA = *(const bf16x8*)(ABASE);                               \
        _Pragma("unroll")                                                   \
        for (int dd = 0; dd < 9; ++dd) {                                    \
            bf16x8 afN = (dd < 8) ? *(const bf16x8*)((ABASE) + (dd + 1) * 512) : afA; \
            const int d3 = dd / 3, d4 = dd - d3 * 3;                        \
            const int imm = (d3 * 27 + d4) * (L2S * 2);                     \
            _Pragma("unroll")                                               \
            for (int j = 0; j < 7; ++j) {                                   \
                if (j < 6 || wave < 2) {                                    \
                    const char* rp = (const char*)sp + (bpo_[j] + imm);     \
                    uint2 p0 = *(const uint2*)rp;                           \
                    uint2 p1 = *(const uint2*)(rp + 8);                     \
                    union { unsigned u[4]; bf16x8 v; } cv;                  \
                    cv.u[0] = p0.x; cv.u[1] = p0.y; cv.u[2] = p1.x; cv.u[3] = p1.y; \
                    acc[j] = __builtin_amdgcn_mfma_f32_16x16x32_bf16(afA, cv.v, acc[j], 0, 0, 0); \
                }                                                           \
            }                                                               \
            afA = afN;                                                      \
        }                                                                   \
    }

__global__ __launch_bounds__(512, 6) void conv4d_mfma_l2(
    const unsigned short* __restrict__ x1, const unsigned short* __restrict__ Ablob,
    const float* __restrict__ bL2, unsigned short* __restrict__ x2)
{
    __shared__ alignas(16) unsigned short sp[L2ROWS * L2S]; // 52992 B
    const int f12 = blockIdx.x, g = blockIdx.y;
    const unsigned short* in = x1 + (size_t)blockIdx.z * 20 * NPOSQ;
    unsigned short* out = x2 + (size_t)blockIdx.z * 20 * NPOSQ;
    const int f1 = f12 / 25, f2 = f12 - f1 * 25;
    const int tid = threadIdx.x, wave = tid >> 6, lane = tid & 63;
    const int lo16 = lane & 15, kqg = (lane >> 4) << 3;
    const int kg = tid & 3;

    f32x4 acc[7];
#pragma unroll
    for (int j = 0; j < 7; ++j) acc[j] = (f32x4){0.f, 0.f, 0.f, 0.f};
    const unsigned short* Ag = Ablob + (size_t)g * 27 * 512;

    STAGE_PRE();

#pragma unroll 1
    for (int kstep = 0; kstep < 3; ++kstep) {
        unsigned poff[8];
        unsigned vmask = 0;
        const int kbase = kstep * 32 + kg * 8;
#pragma unroll
        for (int j = 0; j < 8; ++j) {
            int cie = kbase + j;
            int ci = cie / 9, e = cie - ci * 9;
            int f1n = f1 + e / 3 - 1, f2n = f2 + e % 3 - 1;
            if ((cie < 90) & ((unsigned)f1n < 25u) & ((unsigned)f2n < 25u)) vmask |= (1u << j);
            poff[j] = (unsigned)((g * 10 + ci) * NPOSQ + (f1n * 25 + f2n) * 625);
        }
        __syncthreads();
        STAGE_KSTEP(in);
        __syncthreads();
        const unsigned short* Abase = Ag + (size_t)(kstep * 9) * 512 + lane * 8;
        MFMA_KSTEP(Abase);
    }

    int t = wave;
    for (int j = 0; j < 7; ++j, t += 8) {
        if (t < 50) {
            int f3 = t >> 1, h = t & 1;
            int f4 = h * 16 + lo16;
            if (f4 < 25) {
#pragma unroll
                for (int r = 0; r < 4; ++r) {
                    int co = (lane >> 4) * 4 + r;
                    if (co < 10) {
                        float v = acc[j][r] + bL2[g * 10 + co];
                        out[(size_t)(g * 10 + co) * NPOSQ + f12 * 625 + f3 * 25 + f4] =
                            f2bf(fmaxf(v, 0.0f));
                    }
                }
            }
        }
    }
}

// Layer 3: K=180 (both groups), fused relu-sum, fp32 out to sbuf.
__global__ __launch_bounds__(512, 6) void conv4d_mfma_l3(
    const unsigned short* __restrict__ x2, const unsigned short* __restrict__ Ablob3,
    const float* __restrict__ b3p, float* __restrict__ sbuf)
{
    __shared__ alignas(16) unsigned short sp[L2ROWS * L2S];
    const int f12 = blockIdx.x;
    const unsigned short* in = x2 + (size_t)blockIdx.z * 20 * NPOSQ;
    float* out = sbuf + (size_t)blockIdx.z * NPOSQ;
    const int f1 = f12 / 25, f2 = f12 - f1 * 25;
    const int tid = threadIdx.x, wave = tid >> 6, lane = tid & 63;
    const int lo16 = lane & 15, kqg = (lane >> 4) << 3;
    const int kg = tid & 3;

    f32x4 acc[7];
#pragma unroll
    for (int j = 0; j < 7; ++j) acc[j] = (f32x4){0.f, 0.f, 0.f, 0.f};

    STAGE_PRE();

#pragma unroll 1
    for (int kstep = 0; kstep < 6; ++kstep) {
        unsigned poff[8];
        unsigned vmask = 0;
        const int kbase = kstep * 32 + kg * 8;
#pragma unroll
        for (int j = 0; j < 8; ++j) {
            int cie = kbase + j;
            int plane = cie / 9, e = cie - plane * 9;
            int f1n = f1 + e / 3 - 1, f2n = f2 + e % 3 - 1;
            if ((cie < 180) & ((unsigned)f1n < 25u) & ((unsigned)f2n < 25u)) vmask |= (1u << j);
            poff[j] = (unsigned)(plane * NPOSQ + (f1n * 25 + f2n) * 625);
        }
        __syncthreads();
        STAGE_KSTEP(in);
        __syncthreads();
        const unsigned short* Abase = Ablob3 + (size_t)(kstep * 9) * 512 + lane * 8;
        MFMA_KSTEP(Abase);
    }

    const float b3v = b3p[0];
    if ((lane >> 4) == 0) {
        int t = wave;
        for (int j = 0; j < 7; ++j, t += 8) {
            if (t < 50) {
                int f3 = t >> 1, h = t & 1;
                int f4 = h * 16 + lo16;
                if (f4 < 25) {
                    float s0 = fmaxf(acc[j][0] + b3v, 0.0f);
                    float s1 = fmaxf(acc[j][1] + b3v, 0.0f);
                    out[f12 * 625 + f3 * 25 + f4] = s0 + s1;
                }
            }
        }
    }
}

// ---------------- launch ----------------
extern "C" void kernel_launch(void* const* d_in, const int* in_sizes, int n_in,
                              void* d_out, int out_size, void* d_ws, size_t ws_size,
                              hipStream_t stream)
{
    const float* fA = (const float*)d_in[0];
    const float* fB = (const float*)d_in[1];
    const float* W1 = (const float*)d_in[2];
    const float* b1 = (const float*)d_in[3];
    const float* W2 = (const float*)d_in[4];
    const float* b2 = (const float*)d_in[5];
    const float* W3 = (const float*)d_in[6];
    const float* b3 = (const float*)d_in[7];
    float* out = (float*)d_out;
    float* ws = (float*)d_ws;

    float* invA = ws + 0;        // 2500
    float* invB = ws + 2500;     // 2500
    float* rmax = ws + 5000;     // 2500
    float* cmax = ws + 7500;     // 2500
    float* W1P  = ws + 10000;    // 1620
    float* bL1  = ws + 11620;    // 20
    float* bL2  = ws + 11640;    // 20
    unsigned short* Ablob2 = (unsigned short*)(ws + 12000); // 27648 us
    unsigned short* Ablob3 = (unsigned short*)(ws + 25824); // 27648 us
    float* corr = ws + 40000;    // 1562500
    float* sbuf = ws + 1602500;  // 1562500
    unsigned short* x1b = (unsigned short*)(ws + 3165000);

    const size_t REQ = (size_t)34415000 * 4;
    const bool fused = ws_size >= REQ;
    unsigned short* x2b = fused ? (unsigned short*)(ws + 18790000)
                                : (unsigned short*)(ws + 7080000);

    hipLaunchKernelGGL(pack_misc_kernel, dim3(7), dim3(256), 0, stream, W1, b1, b2, W1P, bL1, bL2);
    hipLaunchKernelGGL(pack_mfma_w2_kernel, dim3(14), dim3(256), 0, stream, W2, Ablob2);
    hipLaunchKernelGGL(pack_mfma_w3_kernel, dim3(14), dim3(256), 0, stream, W3, Ablob3);
    hipLaunchKernelGGL(invnorm_kernel, dim3(10, 2), dim3(256), 0, stream, fA, fB, invA, invB);
    hipLaunchKernelGGL(corr_gemm_kernel, dim3(10, 10, 4), dim3(256), 0, stream,
                       fA, fB, invA, invB, corr);
    hipLaunchKernelGGL(rowmax_kernel, dim3(625), dim3(256), 0, stream, corr, rmax);
    hipLaunchKernelGGL(colmax_kernel, dim3(4, 5), dim3(128), 0, stream, corr, cmax);
    hipLaunchKernelGGL(mm_apply_kernel, dim3(6104), dim3(256), 0, stream, corr, rmax, cmax, corr);

    if (fused) {
        hipLaunchKernelGGL(conv4d_l1, dim3(625, 1, NB), dim3(192), 0, stream, corr, W1P, bL1, x1b);
        hipLaunchKernelGGL(conv4d_mfma_l2, dim3(625, 2, NB), dim3(512), 0, stream,
                           x1b, Ablob2, bL2, x2b);
        hipLaunchKernelGGL(conv4d_mfma_l3, dim3(625, 1, NB), dim3(512), 0, stream,
                           x2b, Ablob3, b3, sbuf);
    } else {
        for (int b = 0; b < NB; ++b) {
            hipLaunchKernelGGL(conv4d_l1, dim3(625, 1, 1), dim3(192), 0, stream,
                               corr + (size_t)b * NPOSQ, W1P, bL1, x1b);
            hipLaunchKernelGGL(conv4d_mfma_l2, dim3(625, 2, 1), dim3(512), 0, stream,
                               x1b, Ablob2, bL2, x2b);
            hipLaunchKernelGGL(conv4d_mfma_l3, dim3(625, 1, 1), dim3(512), 0, stream,
                               x2b, Ablob3, b3, sbuf + (size_t)b * NPOSQ);
        }
    }

    hipLaunchKernelGGL(rowmax_kernel, dim3(625), dim3(256), 0, stream, sbuf, rmax);
    hipLaunchKernelGGL(colmax_kernel, dim3(4, 5), dim3(128), 0, stream, sbuf, cmax);
    hipLaunchKernelGGL(mm_apply_kernel, dim3(6104), dim3(256), 0, stream, sbuf, rmax, cmax, out);
}